// Round 10
// baseline (199.480 us; speedup 1.0000x reference)
//
#include <hip/hip_runtime.h>
#include <cstddef>

// D,H,W,C = 10,200,176,64; convs: (s2,p1) -> (s1,p(0,1,1)) -> (s2,p1)
// Activations channels-last fp16, pixel = 128 B, CHUNK-SWIZZLED within pixel:
//   16B chunk s of pixel at column P stored at position s ^ (P & 7).
// Weights pre-swizzled by co (chunk s of row co at s ^ (co & 7)), staged to
// LDS per tap (B crosses L1/L2 once per block).
//
// R9 -> R10: A-PLANE DOUBLE-BUFFER, staging spread across taps.
// Diagnosis: conv1 invariant at 43-53 us across all structures with MfmaUtil/
// VALUBusy/Occupancy all ~20-30% => latency-bound, and the only un-attacked
// term is the per-kd A restage: 63 KB of global_load_lds issued in one burst,
// transitively drained by the next vmcnt, phase-locked across ~500 blocks
// (HBM bursts ~32 MB/kd-round then idles through the 8 L2-hit B taps;
// measured 1.9 TB/s = 24% of achievable is that signature).
// Fix: block = 8 waves x 1 row/wave (acc 48 regs), LDS = 2 x 64,512 A buffers
// + 2 x 8,192 B buffers = 145,408 -> 1 block/CU. Per tap t<8 each wave issues
// ONE A-chunk DMA for plane kd+1 into la[ab^1] (8x8=64 slots >= 63 chunks)
// + one B(t+1) DMA, then vmcnt(2): in-order vmem retirement means the
// previous tap's A-chunk (issued ~1300 cyc earlier >= HBM latency) is already
// retired -- steady-state stall ~0, and tap0 of kd+1 finds its plane resident.
// Tap sync skeleton (2 barriers/tap, lgkm-drained, sched_barrier fences) is
// byte-identical to the R7/R9-verified structure.
#define HH 200
#define WW 176
#define HP 202
#define WP 178
#define D_IN 10
#define D1 5
#define D2 3
#define D3 2
#define SLICE ((size_t)HP * WP * 64)

// LDS: A dbuf 2 x (10 rows x 50 px x 128 B + 512 pad = 64,512) = 129,024
//    + B dbuf 2 x 8,192 = 16,384  -> 145,408 <= 163,840 -> 1 block/CU, 8 waves
#define LA_BYTES 64512
#define LB_BYTES 8192
#define LDS_TOTAL (2 * LA_BYTES + 2 * LB_BYTES)

typedef _Float16 h8 __attribute__((ext_vector_type(8)));
typedef float f4 __attribute__((ext_vector_type(4)));

__device__ __forceinline__ void gl_lds16(const void* g, void* l) {
    __builtin_amdgcn_global_load_lds(
        (const __attribute__((address_space(1))) void*)g,
        (__attribute__((address_space(3))) void*)l, 16, 0, 0);
}

// ---- prep: halo-zero A2/A3 + weight transform (3 sets) + winner, one launch
// blocks [0,8): halo; [8, 8+1296): wtrans; [1304, ...): winner
__global__ __launch_bounds__(256) void prep_k(const float* __restrict__ W1,
                                              const float* __restrict__ W2,
                                              const float* __restrict__ W3,
                                              _Float16* __restrict__ wdst,
                                              _Float16* __restrict__ A2,
                                              _Float16* __restrict__ A3,
                                              const int* __restrict__ coors,
                                              int* __restrict__ winner, int nvox) {
    const int b = blockIdx.x;
    if (b < 8) {
        _Float16* base = (b < D1) ? (A2 + (size_t)b * SLICE) : (A3 + (size_t)(b - D1) * SLICE);
        const h8 z = {};
        for (int t = threadIdx.x; t < 6080; t += 256) {
            size_t off;
            if (t < 2848) {
                int r = t / 1424, c = t - r * 1424;
                off = (size_t)(r ? (HP - 1) : 0) * WP * 64 + (size_t)c * 8;
            } else {
                int u = t - 2848;
                int c = u / 1616, v = u - c * 1616;
                int hr = v >> 3, o = v & 7;
                off = ((size_t)hr * WP + (c ? (WP - 1) : 0)) * 64 + (size_t)o * 8;
            }
            *(h8*)(base + off) = z;
        }
    } else if (b < 8 + 1296) {
        // OIDHW fp32 -> [set][tap][co][ci swizzled] fp16 (B staged verbatim,
        // chunk s of row co stored at s ^ (co & 7) for conflict-free LDS reads)
        int idx = (b - 8) * 256 + threadIdx.x;
        if (idx < 3 * 27 * 64 * 64) {
            int set = idx / 110592;
            int r = idx - set * 110592;
            const float* src = set == 0 ? W1 : (set == 1 ? W2 : W3);
            int ci = r & 63;
            int co = (r >> 6) & 63;
            int tap = r >> 12;
            int s = ci >> 3, j = ci & 7;
            wdst[set * 110592 + tap * 4096 + co * 64 + (((s ^ (co & 7)) << 3) | j)] =
                (_Float16)src[(co * 64 + ci) * 27 + tap];
        }
    } else {
        int v = (b - 1304) * 256 + threadIdx.x;
        if (v < nvox) {
            int d = coors[v * 4 + 1], h = coors[v * 4 + 2], w = coors[v * 4 + 3];
            atomicMax(&winner[(d * HH + h) * WW + w], v + 1);
        }
    }
}

__global__ __launch_bounds__(256) void scatter_k(const float* __restrict__ feat,
                                                 const int* __restrict__ coors,
                                                 const int* __restrict__ winner,
                                                 _Float16* __restrict__ A, int nvox) {
    int v = blockIdx.x * 4 + (threadIdx.x >> 6);
    int ci = threadIdx.x & 63;
    if (v >= nvox) return;
    int d = coors[v * 4 + 1], h = coors[v * 4 + 2], w = coors[v * 4 + 3];
    if (winner[(d * HH + h) * WW + w] != v + 1) return;
    int P = w + 1;
    int swz = (((ci >> 3) ^ (P & 7)) << 3) | (ci & 7);
    A[(size_t)d * SLICE + ((size_t)(h + 1) * WP + P) * 64 + swz] = (_Float16)feat[v * 64 + ci];
}

// ---- MFMA conv: 8-wave block, A+B double-buffered, staging spread per tap --
// Block = 8 waves; wave i -> output row h0+i, 48 px (mt=3), 64 co (nt=4).
// Prologue: plane(kd_lo) -> la0 (63 glds), B(kd_lo,0) -> lb0.
// Per tap t<8: [kd<kd_hi: 1 A-chunk of plane kd+1 -> la[ab^1]]; 1 B(t+1) gld;
//   vmcnt(2|1) [B(t)+older retired, in-order]; barrier; 24 MFMA; lgkm(0);
//   barrier.  t==8: stage B(kd+1,0) (vmcnt(1)) or drain (vmcnt(0)).
// mfma_f32_16x16x32_f16: A[m=lane&15][k=quad*8+j], D: co=lane&15, px=quad*4+reg
template <int FINAL>
__global__ __launch_bounds__(512, 2) void conv_mfma_k(
    const _Float16* __restrict__ in, void* __restrict__ outp,
    const _Float16* __restrict__ wt,
    const float* __restrict__ scale, const float* __restrict__ bias,
    int inD, int strideD, int padD) {
    __shared__ char smem_raw[LDS_TOTAL];
    char* lb0 = smem_raw + 2 * LA_BYTES;
    char* lb1 = lb0 + LB_BYTES;

    const int lane = threadIdx.x & 63;
    const int wave = threadIdx.x >> 6;   // 0..7
    const int l16 = lane & 15;
    const int quad = lane >> 4;
    const int h0 = blockIdx.y * 8;
    const int wb = blockIdx.x * 48;      // 48 | 8 so (wb+px)&7 == px&7
    const int d = blockIdx.z;

    int kd_lo = padD - d * strideD; if (kd_lo < 0) kd_lo = 0;
    int kd_hi = inD - 1 - d * strideD + padD; if (kd_hi > 2) kd_hi = 2;

    // one A-stage DMA (1 KB): chunk j of plane -> la buffer `abuf`
    auto stage_a1 = [&](const _Float16* aplane, int j, int abuf) {
        int c = j * 64 + lane;
        if (c > 3999) c = 3999;            // dup into 512B pad
        int r = c / 400;
        int rem = c - r * 400;
        int px = rem >> 3, s = rem & 7;
        int g = wb + px; if (g > 177) g = 177;  // ragged edge dup
        gl_lds16(aplane + ((size_t)(h0 + r) * WP + g) * 64 + s * 8,
                 smem_raw + abuf * LA_BYTES + j * 1024);
    };

    f4 acc[3][4];
#pragma unroll
    for (int mt = 0; mt < 3; ++mt)
#pragma unroll
        for (int nt = 0; nt < 4; ++nt) acc[mt][nt] = (f4){0.f, 0.f, 0.f, 0.f};

    int ab = 0;      // la buffer the current kd's taps read
    int base = 0;    // lb parity base (9 taps/kd = odd -> flips per kd)

    // prologue: plane(kd_lo) into la0 (63 chunks over 8 waves, clamp-dup),
    // B(kd_lo,0) into lb0. First tap's vmcnt(2)+barrier makes them visible.
    {
        const _Float16* ap = in + (size_t)(d * strideD + kd_lo - padD) * SLICE;
#pragma unroll
        for (int i = 0; i < 8; ++i) {
            int j = i * 8 + wave; if (j > 62) j = 62;
            stage_a1(ap, j, 0);
        }
        gl_lds16(wt + (size_t)kd_lo * 9 * 4096 + (size_t)(wave * 64 + lane) * 8,
                 lb0 + wave * 1024);
    }

    for (int kd = kd_lo; kd <= kd_hi; ++kd) {
        const int zd = d * strideD + kd - padD;
        const _Float16* __restrict__ wkd = wt + (size_t)kd * 9 * 4096;
        const _Float16* __restrict__ anext = in + (size_t)(zd + 1) * SLICE;
        const _Float16* la = (const _Float16*)(smem_raw + ab * LA_BYTES);

#pragma unroll
        for (int t = 0; t < 9; ++t) {    // tap = kh*3 + kw
            const int kh = t / 3;
            const int kw = t - 3 * kh;
            const int pr = (t & 1) ^ base;
            char* lbR = pr ? lb1 : lb0;
            char* lbW = pr ? lb0 : lb1;

            if (t < 8) {
                if (kd < kd_hi) {        // spread next-plane staging: 1 chunk
                    int j = t * 8 + wave; if (j > 62) j = 62;   // uniform issue
                    stage_a1(anext, j, ab ^ 1);
                }
                // B(kd, t+1); tap stride 4096 ELEMENTS (R5/R6 lesson)
                gl_lds16(wkd + (size_t)(t + 1) * 4096 + (size_t)(wave * 64 + lane) * 8,
                         lbW + wave * 1024);
                if (kd < kd_hi)          // younger-than-B(t): Anext_t + B(t+1)
                    asm volatile("s_waitcnt vmcnt(2)" ::: "memory");
                else                     // younger-than-B(t): B(t+1) only
                    asm volatile("s_waitcnt vmcnt(1)" ::: "memory");
            } else if (kd < kd_hi) {
                // B(kd+1, 0) into lbW (continues parity chain across kd)
                gl_lds16(wkd + (size_t)9 * 4096 + (size_t)(wave * 64 + lane) * 8,
                         lbW + wave * 1024);
                asm volatile("s_waitcnt vmcnt(1)" ::: "memory");
            } else {
                asm volatile("s_waitcnt vmcnt(0)" ::: "memory");
            }
            __builtin_amdgcn_sched_barrier(0);
            __builtin_amdgcn_s_barrier();    // all waves' B(t)/A stages visible
            __builtin_amdgcn_sched_barrier(0);

            const _Float16* lb = (const _Float16*)lbR;
            __builtin_amdgcn_s_setprio(1);
#pragma unroll
            for (int ch = 0; ch < 2; ++ch) {
                const int q = ch * 4 + quad;
                h8 b[4];
#pragma unroll
                for (int nt = 0; nt < 4; ++nt)
                    b[nt] = *(const h8*)(lb + (nt * 16 + l16) * 64 +
                                         ((q ^ (l16 & 7)) << 3));
#pragma unroll
                for (int mt = 0; mt < 3; ++mt) {
                    const int px = mt * 16 + l16 + kw;
                    h8 a = *(const h8*)(la + ((size_t)(wave + kh) * 50 + px) * 64 +
                                        ((q ^ (px & 7)) << 3));
#pragma unroll
                    for (int nt = 0; nt < 4; ++nt)
                        acc[mt][nt] = __builtin_amdgcn_mfma_f32_16x16x32_f16(
                            a, b[nt], acc[mt][nt], 0, 0, 0);
                }
            }
            __builtin_amdgcn_s_setprio(0);
            // drain this wave's ds_reads BEFORE signaling: post-barrier, all
            // waves' reads of la/lbR are retired -> lbW/la[ab^1] reusable.
            asm volatile("s_waitcnt lgkmcnt(0)" ::: "memory");
            __builtin_amdgcn_sched_barrier(0);
            __builtin_amdgcn_s_barrier();
            __builtin_amdgcn_sched_barrier(0);
        }
        ab ^= 1;
        base ^= 1;
    }

    // epilogue: scale+bias+relu; D layout: co=l16(+nt*16), px=mt*16+quad*4+reg
    // (last tap's lgkm-drained barrier => all waves' LDS reads complete)
    const int h = h0 + wave;
    if (FINAL) {
#pragma unroll
        for (int nt = 0; nt < 4; ++nt) {
            const int co = nt * 16 + l16;
            const float s = scale[co];
            const float bb = bias[co];
#pragma unroll
            for (int mt = 0; mt < 3; ++mt) {
                const int w0 = wb + mt * 16 + quad * 4;  // multiple of 4
                if (w0 < WW) {
                    f4 v;
#pragma unroll
                    for (int r = 0; r < 4; ++r) {
                        float x = acc[mt][nt][r] * s + bb;
                        v[r] = x > 0.f ? x : 0.f;
                    }
                    *(f4*)((float*)outp + (((size_t)(co * 2 + d)) * HH + h) * WW + w0) = v;
                }
            }
        }
    } else {
        // LDS bounce: transpose to fp16 rows, then 6 coalesced 1-KB stores.
        // Per-wave region: 48 px x 72 shorts; 8 x 6,912 B = 55,296 <= la0.
        _Float16* ep = (_Float16*)smem_raw + (size_t)wave * (48 * 72);
#pragma unroll
        for (int nt = 0; nt < 4; ++nt) {
            const int co = nt * 16 + l16;
            const float s = scale[co];
            const float bb = bias[co];
#pragma unroll
            for (int mt = 0; mt < 3; ++mt) {
#pragma unroll
                for (int r = 0; r < 4; ++r) {
                    float x = acc[mt][nt][r] * s + bb;
                    x = x > 0.f ? x : 0.f;
                    ep[(mt * 16 + quad * 4 + r) * 72 + co] = (_Float16)x;
                }
            }
        }
        const int lim = (WW - wb) * 8;   // chunk count; 256 for wb=144 else >=384
#pragma unroll
        for (int cv = 0; cv < 6; ++cv) {
            if (cv * 64 < lim) {
                const int c2 = cv * 64 + lane;
                const int pxl = c2 >> 3, s = c2 & 7;
                h8 v = *(const h8*)(ep + pxl * 72 + s * 8);
                const int P = wb + pxl + 1;
                *(h8*)((_Float16*)outp + (size_t)d * SLICE +
                       ((size_t)(h + 1) * WP + P) * 64 + ((s ^ (P & 7)) << 3)) = v;
            }
        }
    }
}

// ---------------- launch ---------------------------------------------------
extern "C" void kernel_launch(void* const* d_in, const int* in_sizes, int n_in,
                              void* d_out, int out_size, void* d_ws, size_t ws_size,
                              hipStream_t stream) {
    const float* feat   = (const float*)d_in[0];
    const int*   coors  = (const int*)d_in[1];
    const float* W1     = (const float*)d_in[3];
    const float* scale1 = (const float*)d_in[4];
    const float* bias1  = (const float*)d_in[5];
    const float* W2     = (const float*)d_in[6];
    const float* scale2 = (const float*)d_in[7];
    const float* bias2  = (const float*)d_in[8];
    const float* W3     = (const float*)d_in[9];
    const float* scale3 = (const float*)d_in[10];
    const float* bias3  = (const float*)d_in[11];
    const int nvox = in_sizes[0] / 64;

    // workspace: [A1][win][A2][A3][wt x3]; memset covers A1+win only
    const size_t nA1 = (size_t)D_IN * SLICE;     // fp16 elems
    const size_t nWin = (size_t)D_IN * HH * WW;  // ints
    const size_t nA2 = (size_t)D1 * SLICE;
    const size_t nA3 = (size_t)D2 * SLICE;
    const size_t nWT = (size_t)27 * 64 * 64;     // fp16 elems per set

    _Float16* A1 = (_Float16*)d_ws;
    int* win = (int*)(A1 + nA1);
    _Float16* A2 = (_Float16*)(win + nWin);
    _Float16* A3 = A2 + nA2;
    _Float16* wt1 = A3 + nA3;
    _Float16* wt2 = wt1 + nWT;
    _Float16* wt3 = wt2 + nWT;

    hipMemsetAsync(d_ws, 0, nA1 * sizeof(_Float16) + nWin * sizeof(int), stream);

    const int win_blk = (nvox + 255) / 256;
    prep_k<<<8 + 1296 + win_blk, 256, 0, stream>>>(W1, W2, W3, wt1, A2, A3,
                                                   coors, win, nvox);
    scatter_k<<<(nvox + 3) / 4, 256, 0, stream>>>(feat, coors, win, A1, nvox);

    dim3 blk(512);
    // conv1: A1(10) -> A2(5)   (500 blocks @ 1/CU)
    conv_mfma_k<0><<<dim3(4, 25, D1), blk, 0, stream>>>(A1, A2, wt1, scale1, bias1, D_IN, 2, 1);
    // conv2: A2(5) -> A3(3)    (300 blocks)
    conv_mfma_k<0><<<dim3(4, 25, D2), blk, 0, stream>>>(A2, A3, wt2, scale2, bias2, D1, 1, 0);
    // conv3: A3(3) -> out planar fp32 (float4 stores)  (200 blocks)
    conv_mfma_k<1><<<dim3(4, 25, D3), blk, 0, stream>>>(A3, (float*)d_out, wt3, scale3, bias3, D2, 2, 1);
}

// Round 11
// 186.642 us; speedup vs baseline: 1.0688x; 1.0688x over previous
//
#include <hip/hip_runtime.h>
#include <cstddef>

// D,H,W,C = 10,200,176,64; convs: (s2,p1) -> (s1,p(0,1,1)) -> (s2,p1)
// Activations channels-last fp16, pixel = 128 B, CHUNK-SWIZZLED within pixel:
//   16B chunk s of pixel at column P stored at position s ^ (P & 7).
// Weights pre-swizzled by co (chunk s of row co at s ^ (co & 7)), staged to
// LDS per tap (B crosses L1/L2 once per block).
//
// R10 -> R11: revert to the R9 base (best measured: 189.9 us; R10's A-dbuf
// cut FETCH 42->37.8 MB but not time -- A-burst theory falsified). Change:
// conv2/conv3 re-tiled from 8-row blocks (300/200 blocks = only 150/100 CUs
// busy at 2/CU) to 4-row blocks (RPW=1, 4 waves x 1 row, R7-verified read
// pattern) -> grids 600/400 fill all 256 CUs and block time halves.
// Sync skeleton / vmcnt constants / B staging / epilogue identical to the
// R9-verified kernel; only constexpr geometry varies via RPW.
#define HH 200
#define WW 176
#define HP 202
#define WP 178
#define D_IN 10
#define D1 5
#define D2 3
#define D3 2
#define SLICE ((size_t)HP * WP * 64)

#define LB_BYTES 8192

typedef _Float16 h8 __attribute__((ext_vector_type(8)));
typedef float f4 __attribute__((ext_vector_type(4)));

__device__ __forceinline__ void gl_lds16(const void* g, void* l) {
    __builtin_amdgcn_global_load_lds(
        (const __attribute__((address_space(1))) void*)g,
        (__attribute__((address_space(3))) void*)l, 16, 0, 0);
}

// ---- prep: halo-zero A2/A3 + weight transform (3 sets) + winner, one launch
// blocks [0,8): halo; [8, 8+1296): wtrans; [1304, ...): winner
__global__ __launch_bounds__(256) void prep_k(const float* __restrict__ W1,
                                              const float* __restrict__ W2,
                                              const float* __restrict__ W3,
                                              _Float16* __restrict__ wdst,
                                              _Float16* __restrict__ A2,
                                              _Float16* __restrict__ A3,
                                              const int* __restrict__ coors,
                                              int* __restrict__ winner, int nvox) {
    const int b = blockIdx.x;
    if (b < 8) {
        _Float16* base = (b < D1) ? (A2 + (size_t)b * SLICE) : (A3 + (size_t)(b - D1) * SLICE);
        const h8 z = {};
        for (int t = threadIdx.x; t < 6080; t += 256) {
            size_t off;
            if (t < 2848) {
                int r = t / 1424, c = t - r * 1424;
                off = (size_t)(r ? (HP - 1) : 0) * WP * 64 + (size_t)c * 8;
            } else {
                int u = t - 2848;
                int c = u / 1616, v = u - c * 1616;
                int hr = v >> 3, o = v & 7;
                off = ((size_t)hr * WP + (c ? (WP - 1) : 0)) * 64 + (size_t)o * 8;
            }
            *(h8*)(base + off) = z;
        }
    } else if (b < 8 + 1296) {
        // OIDHW fp32 -> [set][tap][co][ci swizzled] fp16 (B staged verbatim,
        // chunk s of row co stored at s ^ (co & 7) for conflict-free LDS reads)
        int idx = (b - 8) * 256 + threadIdx.x;
        if (idx < 3 * 27 * 64 * 64) {
            int set = idx / 110592;
            int r = idx - set * 110592;
            const float* src = set == 0 ? W1 : (set == 1 ? W2 : W3);
            int ci = r & 63;
            int co = (r >> 6) & 63;
            int tap = r >> 12;
            int s = ci >> 3, j = ci & 7;
            wdst[set * 110592 + tap * 4096 + co * 64 + (((s ^ (co & 7)) << 3) | j)] =
                (_Float16)src[(co * 64 + ci) * 27 + tap];
        }
    } else {
        int v = (b - 1304) * 256 + threadIdx.x;
        if (v < nvox) {
            int d = coors[v * 4 + 1], h = coors[v * 4 + 2], w = coors[v * 4 + 3];
            atomicMax(&winner[(d * HH + h) * WW + w], v + 1);
        }
    }
}

__global__ __launch_bounds__(256) void scatter_k(const float* __restrict__ feat,
                                                 const int* __restrict__ coors,
                                                 const int* __restrict__ winner,
                                                 _Float16* __restrict__ A, int nvox) {
    int v = blockIdx.x * 4 + (threadIdx.x >> 6);
    int ci = threadIdx.x & 63;
    if (v >= nvox) return;
    int d = coors[v * 4 + 1], h = coors[v * 4 + 2], w = coors[v * 4 + 3];
    if (winner[(d * HH + h) * WW + w] != v + 1) return;
    int P = w + 1;
    int swz = (((ci >> 3) ^ (P & 7)) << 3) | (ci & 7);
    A[(size_t)d * SLICE + ((size_t)(h + 1) * WP + P) * 64 + swz] = (_Float16)feat[v * 64 + ci];
}

// ---- MFMA conv: 4-wave block, RPW rows/wave, B-LDS counted-vmcnt pipeline --
// Block = 4 waves; wave i -> RPW output rows, 48 px, 64 co.
// Per kd: stage A ((4*RPW+2) rows x 50 px glds over 4 waves) + B tap0 (8);
// then 9 taps: stage B(t+1) (2 glds/wave), s_waitcnt vmcnt(2) [own B(t)
// landed], s_barrier, 24*RPW MFMA, lgkmcnt(0) drain, s_barrier (WAR guard).
// mfma_f32_16x16x32_f16: A[m=lane&15][k=quad*8+j], D: co=lane&15, px=quad*4+reg
template <int FINAL, int RPW>
__global__ __launch_bounds__(256, 2) void conv_mfma_k(
    const _Float16* __restrict__ in, void* __restrict__ outp,
    const _Float16* __restrict__ wt,
    const float* __restrict__ scale, const float* __restrict__ bias,
    int inD, int strideD, int padD) {
    constexpr int BROWS = 4 * RPW;                  // output rows per block
    constexpr int AR = BROWS + 2;                   // staged input rows
    constexpr int NSTG = (AR * 400 + 63) / 64;      // A chunks: 63 / 38
    constexpr int LA = NSTG * 1024;                 // 64512 / 38912 (incl pad)
    constexpr int CMAX = AR * 400 - 1;

    __shared__ char smem_raw[LA + 2 * LB_BYTES];
    _Float16* la = (_Float16*)smem_raw;
    char* lb0 = smem_raw + LA;
    char* lb1 = smem_raw + LA + LB_BYTES;

    const int lane = threadIdx.x & 63;
    const int wave = threadIdx.x >> 6;   // 0..3
    const int l16 = lane & 15;
    const int quad = lane >> 4;
    const int h0 = blockIdx.y * BROWS;
    const int wb = blockIdx.x * 48;      // 48 | 8 so (wb+px)&7 == px&7
    const int d = blockIdx.z;

    int kd_lo = padD - d * strideD; if (kd_lo < 0) kd_lo = 0;
    int kd_hi = inD - 1 - d * strideD + padD; if (kd_hi > 2) kd_hi = 2;

    f4 acc[RPW][3][4];
#pragma unroll
    for (int rr = 0; rr < RPW; ++rr)
#pragma unroll
        for (int mt = 0; mt < 3; ++mt)
#pragma unroll
            for (int nt = 0; nt < 4; ++nt) acc[rr][mt][nt] = (f4){0.f, 0.f, 0.f, 0.f};

    for (int kd = kd_lo; kd <= kd_hi; ++kd) {
        const int zd = d * strideD + kd - padD;
        const _Float16* __restrict__ aplane = in + (size_t)zd * SLICE;
        const _Float16* __restrict__ wkd = wt + (size_t)kd * 9 * 4096;

        // stage A: AR rows x 50 px x 8 chunks -> NSTG instrs over 4 waves
        // (WAR vs previous kd's reads guarded by the t=8 lgkm-drained barrier)
        for (int j = wave; j < NSTG; j += 4) {
            int c = j * 64 + lane;
            if (c > CMAX) c = CMAX;            // dup into pad
            int r = c / 400;
            int rem = c - r * 400;
            int px = rem >> 3, s = rem & 7;
            int g = wb + px; if (g > 177) g = 177;  // ragged edge dup
            gl_lds16(aplane + ((size_t)(h0 + r) * WP + g) * 64 + s * 8,
                     smem_raw + j * 1024);
        }
        // stage B tap 0 into lb0 (2 instrs/wave)
#pragma unroll
        for (int i = 0; i < 2; ++i) {
            int k = i * 4 + wave;
            gl_lds16(wkd + (size_t)(k * 64 + lane) * 8, lb0 + k * 1024);
        }

#pragma unroll
        for (int t = 0; t < 9; ++t) {    // tap = kh*3 + kw
            const int kh = t / 3;
            const int kw = t - 3 * kh;
            char* lbc = (t & 1) ? lb1 : lb0;      // t is unroll-constant

            if (t < 8) {
                // stage B(t+1): tap stride 4096 ELEMENTS (R5/R6 lesson)
                char* lbn = (t & 1) ? lb0 : lb1;
#pragma unroll
                for (int i = 0; i < 2; ++i) {
                    int k = i * 4 + wave;
                    gl_lds16(wkd + (size_t)(t + 1) * 4096 + (size_t)(k * 64 + lane) * 8,
                             lbn + k * 1024);
                }
                asm volatile("s_waitcnt vmcnt(2)" ::: "memory");  // B(t)+older done
            } else {
                asm volatile("s_waitcnt vmcnt(0)" ::: "memory");
            }
            __builtin_amdgcn_sched_barrier(0);
            __builtin_amdgcn_s_barrier();    // all waves' stages visible
            __builtin_amdgcn_sched_barrier(0);  // nothing hoists above barrier

            const _Float16* lb = (const _Float16*)lbc;
            __builtin_amdgcn_s_setprio(1);
#pragma unroll
            for (int ch = 0; ch < 2; ++ch) {
                const int q = ch * 4 + quad;
                h8 b[4];
#pragma unroll
                for (int nt = 0; nt < 4; ++nt)
                    b[nt] = *(const h8*)(lb + (nt * 16 + l16) * 64 +
                                         ((q ^ (l16 & 7)) << 3));
#pragma unroll
                for (int rr = 0; rr < RPW; ++rr) {
                    const int row = wave * RPW + rr + kh;
#pragma unroll
                    for (int mt = 0; mt < 3; ++mt) {
                        const int px = mt * 16 + l16 + kw;
                        h8 a = *(const h8*)(la + ((size_t)row * 50 + px) * 64 +
                                            ((q ^ (px & 7)) << 3));
#pragma unroll
                        for (int nt = 0; nt < 4; ++nt)
                            acc[rr][mt][nt] = __builtin_amdgcn_mfma_f32_16x16x32_f16(
                                a, b[nt], acc[rr][mt][nt], 0, 0, 0);
                    }
                }
            }
            __builtin_amdgcn_s_setprio(0);
            // drain this wave's ds_reads BEFORE signaling: after the barrier,
            // every wave's reads of la/lb are complete -> safe to overwrite.
            asm volatile("s_waitcnt lgkmcnt(0)" ::: "memory");
            __builtin_amdgcn_sched_barrier(0);
            __builtin_amdgcn_s_barrier();    // WAR guard: lb[(t+1)&1]/la reusable
            __builtin_amdgcn_sched_barrier(0);
        }
    }

    // epilogue: scale+bias+relu; D layout: co=l16(+nt*16), px=mt*16+quad*4+reg
    // (last tap's lgkm-drained barrier => all waves' LDS reads complete)
    if (FINAL) {
#pragma unroll
        for (int nt = 0; nt < 4; ++nt) {
            const int co = nt * 16 + l16;
            const float s = scale[co];
            const float bb = bias[co];
#pragma unroll
            for (int rr = 0; rr < RPW; ++rr) {
                const int h = h0 + wave * RPW + rr;
#pragma unroll
                for (int mt = 0; mt < 3; ++mt) {
                    const int w0 = wb + mt * 16 + quad * 4;  // multiple of 4
                    if (w0 < WW) {
                        f4 v;
#pragma unroll
                        for (int r = 0; r < 4; ++r) {
                            float x = acc[rr][mt][nt][r] * s + bb;
                            v[r] = x > 0.f ? x : 0.f;
                        }
                        *(f4*)((float*)outp + (((size_t)(co * 2 + d)) * HH + h) * WW + w0) = v;
                    }
                }
            }
        }
    } else {
        // LDS bounce: transpose to fp16 rows, then coalesced 1-KB stores.
        // Per h-row region: 48 px x 72 shorts; BROWS x 6,912 B <= LA.
        _Float16* epb = (_Float16*)smem_raw;
#pragma unroll
        for (int nt = 0; nt < 4; ++nt) {
            const int co = nt * 16 + l16;
            const float s = scale[co];
            const float bb = bias[co];
#pragma unroll
            for (int rr = 0; rr < RPW; ++rr) {
                _Float16* ep = epb + (size_t)(wave * RPW + rr) * (48 * 72);
#pragma unroll
                for (int mt = 0; mt < 3; ++mt) {
#pragma unroll
                    for (int r = 0; r < 4; ++r) {
                        float x = acc[rr][mt][nt][r] * s + bb;
                        x = x > 0.f ? x : 0.f;
                        ep[(mt * 16 + quad * 4 + r) * 72 + co] = (_Float16)x;
                    }
                }
            }
        }
        const int lim = (WW - wb) * 8;   // chunk count; 256 for wb=144 else >=384
#pragma unroll
        for (int rr = 0; rr < RPW; ++rr) {
            const int h = h0 + wave * RPW + rr;
            const _Float16* ep = epb + (size_t)(wave * RPW + rr) * (48 * 72);
#pragma unroll
            for (int cv = 0; cv < 6; ++cv) {
                if (cv * 64 < lim) {
                    const int c2 = cv * 64 + lane;
                    const int pxl = c2 >> 3, s = c2 & 7;
                    h8 v = *(const h8*)(ep + pxl * 72 + s * 8);
                    const int P = wb + pxl + 1;
                    *(h8*)((_Float16*)outp + (size_t)d * SLICE +
                           ((size_t)(h + 1) * WP + P) * 64 + ((s ^ (P & 7)) << 3)) = v;
                }
            }
        }
    }
}

// ---------------- launch ---------------------------------------------------
extern "C" void kernel_launch(void* const* d_in, const int* in_sizes, int n_in,
                              void* d_out, int out_size, void* d_ws, size_t ws_size,
                              hipStream_t stream) {
    const float* feat   = (const float*)d_in[0];
    const int*   coors  = (const int*)d_in[1];
    const float* W1     = (const float*)d_in[3];
    const float* scale1 = (const float*)d_in[4];
    const float* bias1  = (const float*)d_in[5];
    const float* W2     = (const float*)d_in[6];
    const float* scale2 = (const float*)d_in[7];
    const float* bias2  = (const float*)d_in[8];
    const float* W3     = (const float*)d_in[9];
    const float* scale3 = (const float*)d_in[10];
    const float* bias3  = (const float*)d_in[11];
    const int nvox = in_sizes[0] / 64;

    // workspace: [A1][win][A2][A3][wt x3]; memset covers A1+win only
    const size_t nA1 = (size_t)D_IN * SLICE;     // fp16 elems
    const size_t nWin = (size_t)D_IN * HH * WW;  // ints
    const size_t nA2 = (size_t)D1 * SLICE;
    const size_t nA3 = (size_t)D2 * SLICE;
    const size_t nWT = (size_t)27 * 64 * 64;     // fp16 elems per set

    _Float16* A1 = (_Float16*)d_ws;
    int* win = (int*)(A1 + nA1);
    _Float16* A2 = (_Float16*)(win + nWin);
    _Float16* A3 = A2 + nA2;
    _Float16* wt1 = A3 + nA3;
    _Float16* wt2 = wt1 + nWT;
    _Float16* wt3 = wt2 + nWT;

    hipMemsetAsync(d_ws, 0, nA1 * sizeof(_Float16) + nWin * sizeof(int), stream);

    const int win_blk = (nvox + 255) / 256;
    prep_k<<<8 + 1296 + win_blk, 256, 0, stream>>>(W1, W2, W3, wt1, A2, A3,
                                                   coors, win, nvox);
    scatter_k<<<(nvox + 3) / 4, 256, 0, stream>>>(feat, coors, win, A1, nvox);

    dim3 blk(256);
    // conv1: A1(10) -> A2(5)   RPW=2: 8-row blocks, 500 blocks @ 2/CU = 1 round
    conv_mfma_k<0, 2><<<dim3(4, 25, D1), blk, 0, stream>>>(A1, A2, wt1, scale1, bias1, D_IN, 2, 1);
    // conv2: A2(5) -> A3(3)    RPW=1: 4-row blocks, 600 blocks -> all CUs busy
    conv_mfma_k<0, 1><<<dim3(4, 50, D2), blk, 0, stream>>>(A2, A3, wt2, scale2, bias2, D1, 1, 0);
    // conv3: A3(3) -> out planar fp32  RPW=1: 400 blocks -> all CUs busy
    conv_mfma_k<1, 1><<<dim3(4, 50, D3), blk, 0, stream>>>(A3, (float*)d_out, wt3, scale3, bias3, D2, 2, 1);
}